// Round 3
// baseline (100.186 us; speedup 1.0000x reference)
//
#include <hip/hip_runtime.h>

#define NL   10
#define C    64      // contiguous elements per lane (h and x each)
#define OUTW 3072    // valid outputs per wave = 64*C - 1024 halo

__device__ __forceinline__ float fast_tanh(float y) {
    // tanh(y) = 1 - 2/(exp(2y)+1);  exp(2y) = exp2(y * 2*log2(e))
    float e = __builtin_amdgcn_exp2f(y * 2.885390081777927f);
    float r = __builtin_amdgcn_rcpf(e + 1.0f);
    return fmaf(-2.0f, r, 1.0f);   // saturates correctly: e->inf => 1, e->0 => -1
}

// One layer: h[j] = wh0*h[j] + wh1*h[j+D];  x[j] = tanh(h_new[j] + wx0*x[j] + wx1*x[j+D])
// Elements beyond the lane chunk come from lane+1 (D<C) or lane+D/C (D>=C).
// Lane-index wrap produces garbage only in the invalid halo tail -- by construction safe.
template<int D>
__device__ __forceinline__ void layer_step(float (&h)[C], float (&x)[C],
        float wh0, float wh1, float wx0, float wx1, int lane)
{
    if constexpr (D < C) {
        {   // h path: pull old h[0..D) of lane+1 BEFORE overwriting (lockstep-safe)
            float t[D];
            #pragma unroll
            for (int j = 0; j < D; ++j) t[j] = __shfl(h[j], (lane + 1) & 63, 64);
            #pragma unroll
            for (int j = 0; j < C; ++j) {
                float hd = (j + D < C) ? h[j + D] : t[j + D - C];
                h[j] = fmaf(wh0, h[j], wh1 * hd);   // ascending j: h[j+D] still old
            }
        }
        {   // x path: uses NEW h[j] (just computed) and OLD x at +D
            float t[D];
            #pragma unroll
            for (int j = 0; j < D; ++j) t[j] = __shfl(x[j], (lane + 1) & 63, 64);
            #pragma unroll
            for (int j = 0; j < C; ++j) {
                float xd = (j + D < C) ? x[j + D] : t[j + D - C];
                float s  = fmaf(wx0, x[j], h[j]);
                s        = fmaf(wx1, xd, s);
                x[j] = fast_tanh(s);
            }
        }
    } else {
        constexpr int M = D / C;   // whole-chunk lane offset: 1,2,4,8
        #pragma unroll
        for (int j = 0; j < C; ++j) {
            float hd = __shfl(h[j], (lane + M) & 63, 64);  // reads pre-update h[j]
            float xd = __shfl(x[j], (lane + M) & 63, 64);
            float hn = fmaf(wh0, h[j], wh1 * hd);
            float s  = fmaf(wx0, x[j], hn);
            s        = fmaf(wx1, xd, s);
            h[j] = hn;
            x[j] = fast_tanh(s);
        }
    }
}

__global__ __launch_bounds__(64, 1) void rawstack_reg(
    const float* __restrict__ hin, const float* __restrict__ xin,
    const float* __restrict__ wh,  const float* __restrict__ wx,
    float* __restrict__ out, int T, int Lout)
{
    const int lane = threadIdx.x;             // one wave per block
    const int gw   = blockIdx.x;              // wave id within this batch row
    const int b    = blockIdx.y;
    const int W    = gw * OUTW;               // window start in the row

    const float* hb = hin + (size_t)b * T;
    const float* xb = xin + (size_t)b * T;

    // ---- load window into registers: 16 float4 per array, clamped at row end ----
    float h[C], x[C];
    const int cbase = W + lane * C;
    #pragma unroll
    for (int q = 0; q < C / 4; ++q) {
        int e = cbase + q * 4;
        e = (e > T - 4) ? (T - 4) : e;        // clamp: garbage lands in invalid tail only
        float4 hv = *(const float4*)(hb + e);
        float4 xv = *(const float4*)(xb + e);
        h[q*4+0] = hv.x; h[q*4+1] = hv.y; h[q*4+2] = hv.z; h[q*4+3] = hv.w;
        x[q*4+0] = xv.x; x[q*4+1] = xv.y; x[q*4+2] = xv.z; x[q*4+3] = xv.w;
    }

    // ---- 10 layers, fully register-resident ----
    layer_step<  1>(h, x, wh[ 0], wh[ 1], wx[ 0], wx[ 1], lane);
    layer_step<  2>(h, x, wh[ 2], wh[ 3], wx[ 2], wx[ 3], lane);
    layer_step<  4>(h, x, wh[ 4], wh[ 5], wx[ 4], wx[ 5], lane);
    layer_step<  8>(h, x, wh[ 6], wh[ 7], wx[ 6], wx[ 7], lane);
    layer_step< 16>(h, x, wh[ 8], wh[ 9], wx[ 8], wx[ 9], lane);
    layer_step< 32>(h, x, wh[10], wh[11], wx[10], wx[11], lane);
    layer_step< 64>(h, x, wh[12], wh[13], wx[12], wx[13], lane);
    layer_step<128>(h, x, wh[14], wh[15], wx[14], wx[15], lane);
    layer_step<256>(h, x, wh[16], wh[17], wx[16], wx[17], lane);
    layer_step<512>(h, x, wh[18], wh[19], wx[18], wx[19], lane);

    // ---- store: lanes 0..47 hold the 3072 valid outputs ----
    if (lane < 48) {
        float* ob = out + (size_t)b * Lout;
        const int s0 = W + lane * C;
        if (s0 + C <= Lout) {
            #pragma unroll
            for (int j = 0; j < C; ++j) ob[s0 + j] = x[j];
        } else {
            #pragma unroll
            for (int j = 0; j < C; ++j) if (s0 + j < Lout) ob[s0 + j] = x[j];
        }
    }
}

extern "C" void kernel_launch(void* const* d_in, const int* in_sizes, int n_in,
                              void* d_out, int out_size, void* d_ws, size_t ws_size,
                              hipStream_t stream) {
    const float* h  = (const float*)d_in[0];
    const float* x  = (const float*)d_in[1];
    const float* wh = (const float*)d_in[2];
    const float* wx = (const float*)d_in[3];
    float* out = (float*)d_out;

    const int B    = 64;
    const int T    = in_sizes[0] / B;   // 131072
    const int Lout = out_size / B;      // 130049

    const int wavesPerRow = (Lout + OUTW - 1) / OUTW;   // 43

    dim3 grid(wavesPerRow, B);
    rawstack_reg<<<grid, 64, 0, stream>>>(h, x, wh, wx, out, T, Lout);
}